// Round 1
// baseline (197.163 us; speedup 1.0000x reference)
//
#include <hip/hip_runtime.h>
#include <hip/hip_bf16.h>

#define D 128
#define CAT 640
#define BM 32        // batch rows per block
#define KS1 20       // 640/32 k-steps for GEMM1
#define KS2 4        // 128/32 k-steps for GEMM2
#define W1F_ELEMS 81920   // 20*8*64*8
#define W2F_ELEMS 16384   // 4*8*64*8

typedef __attribute__((ext_vector_type(8))) short bf16x8;
typedef __attribute__((ext_vector_type(4))) short short4v;
typedef __attribute__((ext_vector_type(4))) float f32x4;

static __device__ __forceinline__ unsigned short f32_to_bf16(float f) {
    unsigned u = __float_as_uint(f);
    unsigned r = u + 0x7FFFu + ((u >> 16) & 1u);   // RNE
    return (unsigned short)(r >> 16);
}

// Pack W1 [128][640] and W2 [128][128] (fp32, row-major, torch Linear [out,in])
// into MFMA B-operand fragment order:
//   frag element (ks, j16, lane, e) = W[o = j16*16 + (lane&15)][k = ks*32 + (lane>>4)*8 + e]
// so a wave's global_load_dwordx4 at ((ks*8+j16)*64 + lane)*16B is a ready B fragment.
__global__ void prep_frags(const float* __restrict__ W1, const float* __restrict__ W2,
                           unsigned short* __restrict__ W1f, unsigned short* __restrict__ W2f) {
    int f = blockIdx.x * 256 + threadIdx.x;
    if (f < W1F_ELEMS) {
        int e = f & 7, l = (f >> 3) & 63, j16 = (f >> 9) & 7, ks = f >> 12;
        int o = j16 * 16 + (l & 15);
        int k = ks * 32 + ((l >> 4) << 3) + e;
        W1f[f] = f32_to_bf16(W1[o * CAT + k]);
    } else if (f < W1F_ELEMS + W2F_ELEMS) {
        int f2 = f - W1F_ELEMS;
        int e = f2 & 7, l = (f2 >> 3) & 63, j16 = (f2 >> 9) & 7, ks = f2 >> 12;
        int o = j16 * 16 + (l & 15);
        int k = ks * 32 + ((l >> 4) << 3) + e;
        W2f[f2] = f32_to_bf16(W2[o * D + k]);
    }
}

__global__ __launch_bounds__(256) void rowmlp_kernel(
    const float* __restrict__ x_rows, const int* __restrict__ seeds,
    const unsigned short* __restrict__ W1f, const float* __restrict__ b1,
    const unsigned short* __restrict__ W2f, const float* __restrict__ b2,
    float* __restrict__ out, int B, int Nrows)
{
    // XOR-swizzle (G4): short-index ^= (row&7)<<3  (== byte ^ (row&7)<<4)
    // breaks the 16-way bank conflict of row-stride-1280B/256B ds_read_b128.
    __shared__ __align__(16) unsigned short Abuf[BM * CAT];  // 40 KB
    __shared__ __align__(16) unsigned short Hbuf[BM * D];    // 8 KB
    __shared__ int sseed[BM];

    const int tid = threadIdx.x;
    const int blk = blockIdx.x;

    if (tid < BM) sseed[tid] = seeds[blk * BM + tid];
    __syncthreads();

    // ---- Phase 1: gather 32 rows x 5 neighbors x 128 fp32 -> bf16 LDS tile
    {
        const int lane32 = tid & 31;
        const int segbase = tid >> 5;          // 8 segments (row,j) per iter
        #pragma unroll
        for (int it = 0; it < BM * 5 / 8; ++it) {
            int seg = it * 8 + segbase;        // 0..159
            int row = seg / 5;
            int j = seg - row * 5;
            int idx = sseed[row] + j - 2;
            idx = idx < 0 ? 0 : (idx >= Nrows ? Nrows - 1 : idx);
            float4 v = *((const float4*)(x_rows + (size_t)idx * D) + lane32);
            short4v p;
            p.x = (short)f32_to_bf16(v.x);
            p.y = (short)f32_to_bf16(v.y);
            p.z = (short)f32_to_bf16(v.z);
            p.w = (short)f32_to_bf16(v.w);
            int kshort = j * D + lane32 * 4;
            int off = row * CAT + (kshort ^ ((row & 7) << 3));
            *(short4v*)(&Abuf[off]) = p;
        }
    }
    __syncthreads();

    const int wave = tid >> 6;   // 0..3 == N-column group (wave covers cols wave*32..+31)
    const int l    = tid & 63;
    const int l15  = l & 15;
    const int lhi  = l >> 4;

    // ---- Phase 2: GEMM1  h = x_cat @ W1^T   (M=32 N=128 K=640)
    f32x4 acc[2][2] = {};
    #pragma unroll
    for (int ks = 0; ks < KS1; ++ks) {
        bf16x8 a[2], b[2];
        #pragma unroll
        for (int m = 0; m < 2; ++m) {
            int row = m * 16 + l15;
            int kshort = ks * 32 + lhi * 8;
            a[m] = *(const bf16x8*)(&Abuf[row * CAT + (kshort ^ ((row & 7) << 3))]);
        }
        #pragma unroll
        for (int n = 0; n < 2; ++n) {
            int j16 = wave * 2 + n;
            b[n] = ((const bf16x8*)W1f)[(ks * 8 + j16) * 64 + l];
        }
        #pragma unroll
        for (int m = 0; m < 2; ++m)
            #pragma unroll
            for (int n = 0; n < 2; ++n)
                acc[m][n] = __builtin_amdgcn_mfma_f32_16x16x32_bf16(a[m], b[n], acc[m][n], 0, 0, 0);
    }

    // ---- Phase 3: bias + ReLU -> bf16 h tile in LDS (swizzled like Abuf)
    #pragma unroll
    for (int n = 0; n < 2; ++n) {
        int col = wave * 32 + n * 16 + l15;
        float bias = b1[col];
        #pragma unroll
        for (int m = 0; m < 2; ++m) {
            #pragma unroll
            for (int r = 0; r < 4; ++r) {
                float v = acc[m][n][r] + bias;
                v = v > 0.f ? v : 0.f;
                int row = m * 16 + lhi * 4 + r;   // D layout: col=lane&15, row=(lane>>4)*4+reg
                Hbuf[row * D + (col ^ ((row & 7) << 3))] = f32_to_bf16(v);
            }
        }
    }
    __syncthreads();

    // ---- Phase 4: GEMM2  out = h @ W2^T   (M=32 N=128 K=128)
    f32x4 acc2[2][2] = {};
    #pragma unroll
    for (int ks = 0; ks < KS2; ++ks) {
        bf16x8 a[2], b[2];
        #pragma unroll
        for (int m = 0; m < 2; ++m) {
            int row = m * 16 + l15;
            int kshort = ks * 32 + lhi * 8;
            a[m] = *(const bf16x8*)(&Hbuf[row * D + (kshort ^ ((row & 7) << 3))]);
        }
        #pragma unroll
        for (int n = 0; n < 2; ++n) {
            int j16 = wave * 2 + n;
            b[n] = ((const bf16x8*)W2f)[(ks * 8 + j16) * 64 + l];
        }
        #pragma unroll
        for (int m = 0; m < 2; ++m)
            #pragma unroll
            for (int n = 0; n < 2; ++n)
                acc2[m][n] = __builtin_amdgcn_mfma_f32_16x16x32_bf16(a[m], b[n], acc2[m][n], 0, 0, 0);
    }

    // ---- Phase 5: bias + store fp32
    #pragma unroll
    for (int n = 0; n < 2; ++n) {
        int col = wave * 32 + n * 16 + l15;
        float bias = b2[col];
        #pragma unroll
        for (int m = 0; m < 2; ++m) {
            #pragma unroll
            for (int r = 0; r < 4; ++r) {
                int row = m * 16 + lhi * 4 + r;
                out[(size_t)(blk * BM + row) * D + col] = acc2[m][n][r] + bias;
            }
        }
    }
}

extern "C" void kernel_launch(void* const* d_in, const int* in_sizes, int n_in,
                              void* d_out, int out_size, void* d_ws, size_t ws_size,
                              hipStream_t stream) {
    const float* x_rows = (const float*)d_in[0];
    const int*   seeds  = (const int*)d_in[1];
    const float* W1     = (const float*)d_in[2];
    const float* b1     = (const float*)d_in[3];
    const float* W2     = (const float*)d_in[4];
    const float* b2     = (const float*)d_in[5];
    float* out = (float*)d_out;

    int Nrows = in_sizes[0] / D;
    int B = in_sizes[1];

    unsigned short* W1f = (unsigned short*)d_ws;
    unsigned short* W2f = W1f + W1F_ELEMS;

    prep_frags<<<(W1F_ELEMS + W2F_ELEMS + 255) / 256, 256, 0, stream>>>(W1, W2, W1f, W2f);
    rowmlp_kernel<<<B / BM, 256, 0, stream>>>(x_rows, seeds, W1f, b1, W2f, b2, out, B, Nrows);
}